// Round 2
// baseline (1094.611 us; speedup 1.0000x reference)
//
#include <hip/hip_runtime.h>
#include <hip/hip_bf16.h>

#define N_USERS 30000
#define N_NODES 100000
#define DIM 64
#define N_EDGES 1600000

typedef __hip_bfloat16 bf16;

__device__ __forceinline__ float b2f(bf16 v) { return __bfloat162float(v); }
__device__ __forceinline__ bf16 f2b(float v) { return __float2bfloat16(v); }

// dtype-flexible load/store: f32 flag selects float* vs bf16* interpretation
__device__ __forceinline__ float ld(const void* p, int i, int f32) {
    return f32 ? ((const float*)p)[i] : b2f(((const bf16*)p)[i]);
}
__device__ __forceinline__ void st(void* p, int i, float v, int f32) {
    if (f32) ((float*)p)[i] = v; else ((bf16*)p)[i] = f2b(v);
}

// ---------------------------------------------------------------------------
// Detect fp32 vs bf16 per tensor. A bf16 tensor (values ~N(0,0.1)) read as
// fp32 has exponent bits from bf16 bits[14:7] -> |v| ~ 2^119; genuine fp32
// data of this problem is all |v| < 1. flags: 0=user,1=entity,2=vals,3=weights
// ---------------------------------------------------------------------------
__global__ void k_detect(const void* user, const void* ent, const void* vals,
                         const void* W, int* flags) {
    if (threadIdx.x == 0 && blockIdx.x == 0) {
        const void* ps[4] = { user, ent, vals, W };
        for (int t = 0; t < 4; ++t) {
            const float* f = (const float*)ps[t];
            int ok = 0;
            for (int i = 0; i < 32; ++i) {
                float v = f[i];
                if (v == v && fabsf(v) <= 1e4f) ok++;
            }
            flags[t] = (ok >= 16) ? 1 : 0;
        }
    }
}

// ---------------------------------------------------------------------------
// out[:, :64] = concat(user, entity); side = 0
// ---------------------------------------------------------------------------
__global__ void k_init(const void* __restrict__ user, const void* __restrict__ ent,
                       void* __restrict__ out, float* __restrict__ side,
                       const int* __restrict__ flags) {
    int i = blockIdx.x * blockDim.x + threadIdx.x;
    if (i >= N_NODES * DIM) return;
    int fo = flags[0], fe = flags[1];
    int n = i >> 6, d = i & 63;
    float v = (n < N_USERS) ? ld(user, i, fo) : ld(ent, i - N_USERS * DIM, fe);
    st(out, n * 160 + d, v, fo);
    side[i] = 0.0f;
}

// ---------------------------------------------------------------------------
// SpMM: side[row] += val * x[col]; x read from out[:, off:off+64]
// one wave per edge, lane = feature dim
// ---------------------------------------------------------------------------
__global__ void k_spmm(const int* __restrict__ rows, const int* __restrict__ cols,
                       const void* __restrict__ vals, const void* __restrict__ out,
                       float* __restrict__ side, const int* __restrict__ flags,
                       int off) {
    int e = blockIdx.x * (blockDim.x >> 6) + (threadIdx.x >> 6);
    if (e >= N_EDGES) return;
    int lane = threadIdx.x & 63;
    int fo = flags[0], fv = flags[2];
    int r = rows[e], c = cols[e];
    float v = ld(vals, e, fv);
    float xv = ld(out, c * 160 + off + lane, fo);
    atomicAdd(&side[r * DIM + lane], v * xv);
}

// ---------------------------------------------------------------------------
// Layer 1 combine 64->64: reads ego from out[:,0:64], writes out[:,64:128],
// zeroes side for layer 2. 4 nodes per 256-thread block.
// ---------------------------------------------------------------------------
__global__ __launch_bounds__(256) void k_combine1(
    const void* __restrict__ W1, const void* __restrict__ b1,
    const void* __restrict__ W2, const void* __restrict__ b2,
    void* __restrict__ out, float* __restrict__ side,
    const int* __restrict__ flags) {
    __shared__ float W1s[64][64];
    __shared__ float W2s[64][64];
    __shared__ float b1s[64], b2s[64];
    __shared__ float hp[4][64], hm[4][64];
    int t = threadIdx.x;
    int fo = flags[0], fw = flags[3];
    for (int i = t; i < 4096; i += 256) {
        W1s[i >> 6][i & 63] = ld(W1, i, fw);
        W2s[i >> 6][i & 63] = ld(W2, i, fw);
    }
    if (t < 64) { b1s[t] = ld(b1, t, fw); b2s[t] = ld(b2, t, fw); }
    int g = t >> 6, d = t & 63;
    int n = blockIdx.x * 4 + g;
    float h = ld(out, n * 160 + d, fo);
    float s = side[n * DIM + d];
    side[n * DIM + d] = 0.0f;          // reset accumulator for layer 2
    hp[g][d] = h + s;
    hm[g][d] = h * s;
    __syncthreads();
    float a1 = b1s[d], a2 = b2s[d];
#pragma unroll
    for (int k = 0; k < 64; ++k) {
        a1 += hp[g][k] * W1s[k][d];
        a2 += hm[g][k] * W2s[k][d];
    }
    a1 = a1 > 0.0f ? a1 : 0.01f * a1;
    a2 = a2 > 0.0f ? a2 : 0.01f * a2;
    float v = a1 + a2;
    float ss = v * v;
#pragma unroll
    for (int m = 1; m < 64; m <<= 1) ss += __shfl_xor(ss, m, 64);
    float inv = 1.0f / fmaxf(sqrtf(ss), 1e-12f);
    st(out, n * 160 + 64 + d, v * inv, fo);
}

// ---------------------------------------------------------------------------
// Layer 2 combine 64->32: reads ego from out[:,64:128], writes out[:,128:160].
// Lanes 0..31 compute sum_e, lanes 32..63 compute bi_e.
// ---------------------------------------------------------------------------
__global__ __launch_bounds__(256) void k_combine2(
    const void* __restrict__ W1, const void* __restrict__ b1,
    const void* __restrict__ W2, const void* __restrict__ b2,
    void* __restrict__ out, const float* __restrict__ side,
    const int* __restrict__ flags) {
    __shared__ float W1s[64][32];
    __shared__ float W2s[64][32];
    __shared__ float b1s[32], b2s[32];
    __shared__ float hp[4][64], hm[4][64];
    int t = threadIdx.x;
    int fo = flags[0], fw = flags[3];
    for (int i = t; i < 2048; i += 256) {
        W1s[i >> 5][i & 31] = ld(W1, i, fw);
        W2s[i >> 5][i & 31] = ld(W2, i, fw);
    }
    if (t < 32) { b1s[t] = ld(b1, t, fw); b2s[t] = ld(b2, t, fw); }
    int g = t >> 6, lane = t & 63;
    int n = blockIdx.x * 4 + g;
    float h = ld(out, n * 160 + 64 + lane, fo);
    float s = side[n * DIM + lane];
    hp[g][lane] = h + s;
    hm[g][lane] = h * s;
    __syncthreads();
    int d = lane & 31;
    bool hi = lane >= 32;
    float acc = hi ? b2s[d] : b1s[d];
    const float(*Ws)[32] = hi ? W2s : W1s;
    const float* in = hi ? hm[g] : hp[g];
#pragma unroll
    for (int k = 0; k < 64; ++k) acc += in[k] * Ws[k][d];
    acc = acc > 0.0f ? acc : 0.01f * acc;
    float v = acc + __shfl_xor(acc, 32, 64);   // t1[d] + t2[d], mirrored halves
    float ss = v * v;
#pragma unroll
    for (int m = 1; m < 32; m <<= 1) ss += __shfl_xor(ss, m, 64);
    float inv = 1.0f / fmaxf(sqrtf(ss), 1e-12f);
    if (!hi) st(out, n * 160 + 128 + d, v * inv, fo);
}

extern "C" void kernel_launch(void* const* d_in, const int* in_sizes, int n_in,
                              void* d_out, int out_size, void* d_ws, size_t ws_size,
                              hipStream_t stream) {
    const void* user = d_in[0];
    const void* ent  = d_in[1];
    const void* vals = d_in[2];
    const void* W1_1 = d_in[3];
    const void* b1_1 = d_in[4];
    const void* W2_1 = d_in[5];
    const void* b2_1 = d_in[6];
    const void* W1_2 = d_in[7];
    const void* b1_2 = d_in[8];
    const void* W2_2 = d_in[9];
    const void* b2_2 = d_in[10];
    const int* rows  = (const int*)d_in[11];
    const int* cols  = (const int*)d_in[12];

    // ws layout: [flags: 4 ints, padded to 256 B][side: f32 N*64 = 25.6 MB]
    int* flags = (int*)d_ws;
    float* side = (float*)((char*)d_ws + 256);

    k_detect<<<1, 64, 0, stream>>>(user, ent, vals, W1_1, flags);
    k_init<<<(N_NODES * DIM + 255) / 256, 256, 0, stream>>>(user, ent, d_out, side, flags);
    k_spmm<<<(N_EDGES + 3) / 4, 256, 0, stream>>>(rows, cols, vals, d_out, side, flags, 0);
    k_combine1<<<N_NODES / 4, 256, 0, stream>>>(W1_1, b1_1, W2_1, b2_1, d_out, side, flags);
    k_spmm<<<(N_EDGES + 3) / 4, 256, 0, stream>>>(rows, cols, vals, d_out, side, flags, 64);
    k_combine2<<<N_NODES / 4, 256, 0, stream>>>(W1_2, b1_2, W2_2, b2_2, d_out, side, flags);
}

// Round 3
// 885.704 us; speedup vs baseline: 1.2359x; 1.2359x over previous
//
#include <hip/hip_runtime.h>
#include <hip/hip_bf16.h>

#define N_USERS 30000
#define N_NODES 100000
#define DIM 64
#define N_EDGES 1600000
#define SCAN_ELEMS 2048
#define SCAN_NB ((N_NODES + SCAN_ELEMS - 1) / SCAN_ELEMS)  // 49

typedef __hip_bfloat16 bf16;

__device__ __forceinline__ float b2f(bf16 v) { return __bfloat162float(v); }
__device__ __forceinline__ bf16 f2b(float v) { return __float2bfloat16(v); }

// dtype-flexible load/store: f32 flag selects float* vs bf16* interpretation
__device__ __forceinline__ float ld(const void* p, int i, int f32) {
    return f32 ? ((const float*)p)[i] : b2f(((const bf16*)p)[i]);
}
__device__ __forceinline__ void st(void* p, int i, float v, int f32) {
    if (f32) ((float*)p)[i] = v; else ((bf16*)p)[i] = f2b(v);
}

// ---------------------------------------------------------------------------
// Detect fp32 vs bf16 per tensor (bf16 bits read as fp32 -> huge exponents).
// flags: 0=embeddings/out world, 1=entity, 2=vals, 3=weights
// ---------------------------------------------------------------------------
__global__ void k_detect(const void* user, const void* ent, const void* vals,
                         const void* W, int* flags) {
    if (threadIdx.x == 0 && blockIdx.x == 0) {
        const void* ps[4] = { user, ent, vals, W };
        for (int t = 0; t < 4; ++t) {
            const float* f = (const float*)ps[t];
            int ok = 0;
            for (int i = 0; i < 32; ++i) {
                float v = f[i];
                if (v == v && fabsf(v) <= 1e4f) ok++;
            }
            flags[t] = (ok >= 16) ? 1 : 0;
        }
    }
}

// ---------------------------------------------------------------------------
// CSR build: zero counters -> histogram -> 3-phase exclusive scan -> scatter
// ---------------------------------------------------------------------------
__global__ void k_zero(int* __restrict__ cnt) {
    int i = blockIdx.x * blockDim.x + threadIdx.x;
    if (i <= N_NODES) cnt[i] = 0;
}

__global__ void k_hist(const int* __restrict__ rows, int* __restrict__ cnt) {
    int e = blockIdx.x * blockDim.x + threadIdx.x;
    if (e < N_EDGES) atomicAdd(&cnt[rows[e]], 1);
}

// per-block exclusive scan (in-place over cnt), block totals to partials
__global__ __launch_bounds__(256) void k_scan1(int* __restrict__ cnt,
                                               int* __restrict__ partials) {
    __shared__ int lds[256];
    int t = threadIdx.x;
    int base = blockIdx.x * SCAN_ELEMS + t * 8;
    int local[8];
    int sum = 0;
#pragma unroll
    for (int i = 0; i < 8; ++i) {
        int idx = base + i;
        int v = (idx < N_NODES) ? cnt[idx] : 0;
        local[i] = sum;
        sum += v;
    }
    lds[t] = sum;
    __syncthreads();
    for (int off = 1; off < 256; off <<= 1) {
        int v = (t >= off) ? lds[t - off] : 0;
        __syncthreads();
        lds[t] += v;
        __syncthreads();
    }
    int texcl = (t == 0) ? 0 : lds[t - 1];
#pragma unroll
    for (int i = 0; i < 8; ++i) {
        int idx = base + i;
        if (idx < N_NODES) cnt[idx] = texcl + local[i];
    }
    if (t == 255) partials[blockIdx.x] = lds[255];
}

__global__ void k_scan2(int* __restrict__ partials) {
    if (threadIdx.x == 0 && blockIdx.x == 0) {
        int run = 0;
        for (int i = 0; i < SCAN_NB; ++i) { int v = partials[i]; partials[i] = run; run += v; }
        partials[SCAN_NB] = run;  // total == N_EDGES
    }
}

__global__ void k_scan3(int* __restrict__ cnt, int* __restrict__ cursor,
                        const int* __restrict__ partials) {
    int i = blockIdx.x * blockDim.x + threadIdx.x;
    if (i < N_NODES) {
        int v = cnt[i] + partials[i / SCAN_ELEMS];
        cnt[i] = v;
        cursor[i] = v;
    } else if (i == N_NODES) {
        cnt[N_NODES] = partials[SCAN_NB];
    }
}

__global__ void k_scatter(const int* __restrict__ rows, const int* __restrict__ cols,
                          const void* __restrict__ vals, int* __restrict__ cursor,
                          int* __restrict__ scol, float* __restrict__ sval,
                          const int* __restrict__ flags) {
    int e = blockIdx.x * blockDim.x + threadIdx.x;
    if (e >= N_EDGES) return;
    int fv = flags[2];
    int pos = atomicAdd(&cursor[rows[e]], 1);
    scol[pos] = cols[e];
    sval[pos] = ld(vals, e, fv);
}

// ---------------------------------------------------------------------------
// out[:, :64] = concat(user, entity)
// ---------------------------------------------------------------------------
__global__ void k_init(const void* __restrict__ user, const void* __restrict__ ent,
                       void* __restrict__ out, const int* __restrict__ flags) {
    int i = blockIdx.x * blockDim.x + threadIdx.x;
    if (i >= N_NODES * DIM) return;
    int fo = flags[0], fe = flags[1];
    int n = i >> 6, d = i & 63;
    float v = (n < N_USERS) ? ld(user, i, fo) : ld(ent, i - N_USERS * DIM, fe);
    st(out, n * 160 + d, v, fo);
}

// ---------------------------------------------------------------------------
// Layer 1 fused: per-wave CSR side accumulation + bi-interaction 64->64.
// 4 nodes per 256-thread block (wave g = node), lane = dim.
// Reads ego from out[:,0:64], writes out[:,64:128].
// ---------------------------------------------------------------------------
__global__ __launch_bounds__(256) void k_layer1(
    const void* __restrict__ W1, const void* __restrict__ b1,
    const void* __restrict__ W2, const void* __restrict__ b2,
    void* __restrict__ out, const int* __restrict__ row_start,
    const int* __restrict__ scol, const float* __restrict__ sval,
    const int* __restrict__ flags) {
    __shared__ float W1s[64][64];
    __shared__ float W2s[64][64];
    __shared__ float b1s[64], b2s[64];
    __shared__ float hp[4][64], hm[4][64];
    int t = threadIdx.x;
    int fo = flags[0], fw = flags[3];
    for (int i = t; i < 4096; i += 256) {
        W1s[i >> 6][i & 63] = ld(W1, i, fw);
        W2s[i >> 6][i & 63] = ld(W2, i, fw);
    }
    if (t < 64) { b1s[t] = ld(b1, t, fw); b2s[t] = ld(b2, t, fw); }
    int g = t >> 6, lane = t & 63;
    int n = blockIdx.x * 4 + g;
    int s = row_start[n], e = row_start[n + 1];
    float acc0 = 0.0f, acc1 = 0.0f;
    int j = s;
    for (; j + 1 < e; j += 2) {
        int c0 = scol[j], c1 = scol[j + 1];
        float v0 = sval[j], v1 = sval[j + 1];
        acc0 += v0 * ld(out, c0 * 160 + lane, fo);
        acc1 += v1 * ld(out, c1 * 160 + lane, fo);
    }
    if (j < e) acc0 += sval[j] * ld(out, scol[j] * 160 + lane, fo);
    float sde = acc0 + acc1;
    float h = ld(out, n * 160 + lane, fo);
    hp[g][lane] = h + sde;
    hm[g][lane] = h * sde;
    __syncthreads();
    float a1 = b1s[lane], a2 = b2s[lane];
#pragma unroll
    for (int k = 0; k < 64; ++k) {
        a1 += hp[g][k] * W1s[k][lane];
        a2 += hm[g][k] * W2s[k][lane];
    }
    a1 = a1 > 0.0f ? a1 : 0.01f * a1;
    a2 = a2 > 0.0f ? a2 : 0.01f * a2;
    float v = a1 + a2;
    float ss = v * v;
#pragma unroll
    for (int m = 1; m < 64; m <<= 1) ss += __shfl_xor(ss, m, 64);
    float inv = 1.0f / fmaxf(sqrtf(ss), 1e-12f);
    st(out, n * 160 + 64 + lane, v * inv, fo);
}

// ---------------------------------------------------------------------------
// Layer 2 fused: CSR side accumulation + bi-interaction 64->32.
// Reads ego from out[:,64:128], writes out[:,128:160].
// Lanes 0..31 compute sum_e, lanes 32..63 compute bi_e.
// ---------------------------------------------------------------------------
__global__ __launch_bounds__(256) void k_layer2(
    const void* __restrict__ W1, const void* __restrict__ b1,
    const void* __restrict__ W2, const void* __restrict__ b2,
    void* __restrict__ out, const int* __restrict__ row_start,
    const int* __restrict__ scol, const float* __restrict__ sval,
    const int* __restrict__ flags) {
    __shared__ float W1s[64][32];
    __shared__ float W2s[64][32];
    __shared__ float b1s[32], b2s[32];
    __shared__ float hp[4][64], hm[4][64];
    int t = threadIdx.x;
    int fo = flags[0], fw = flags[3];
    for (int i = t; i < 2048; i += 256) {
        W1s[i >> 5][i & 31] = ld(W1, i, fw);
        W2s[i >> 5][i & 31] = ld(W2, i, fw);
    }
    if (t < 32) { b1s[t] = ld(b1, t, fw); b2s[t] = ld(b2, t, fw); }
    int g = t >> 6, lane = t & 63;
    int n = blockIdx.x * 4 + g;
    int s = row_start[n], e = row_start[n + 1];
    float acc0 = 0.0f, acc1 = 0.0f;
    int j = s;
    for (; j + 1 < e; j += 2) {
        int c0 = scol[j], c1 = scol[j + 1];
        float v0 = sval[j], v1 = sval[j + 1];
        acc0 += v0 * ld(out, c0 * 160 + 64 + lane, fo);
        acc1 += v1 * ld(out, c1 * 160 + 64 + lane, fo);
    }
    if (j < e) acc0 += sval[j] * ld(out, scol[j] * 160 + 64 + lane, fo);
    float sde = acc0 + acc1;
    float h = ld(out, n * 160 + 64 + lane, fo);
    hp[g][lane] = h + sde;
    hm[g][lane] = h * sde;
    __syncthreads();
    int d = lane & 31;
    bool hi = lane >= 32;
    float acc = hi ? b2s[d] : b1s[d];
    const float(*Ws)[32] = hi ? W2s : W1s;
    const float* in = hi ? hm[g] : hp[g];
#pragma unroll
    for (int k = 0; k < 64; ++k) acc += in[k] * Ws[k][d];
    acc = acc > 0.0f ? acc : 0.01f * acc;
    float v = acc + __shfl_xor(acc, 32, 64);
    float ss = v * v;
#pragma unroll
    for (int m = 1; m < 32; m <<= 1) ss += __shfl_xor(ss, m, 64);
    float inv = 1.0f / fmaxf(sqrtf(ss), 1e-12f);
    if (!hi) st(out, n * 160 + 128 + d, v * inv, fo);
}

extern "C" void kernel_launch(void* const* d_in, const int* in_sizes, int n_in,
                              void* d_out, int out_size, void* d_ws, size_t ws_size,
                              hipStream_t stream) {
    const void* user = d_in[0];
    const void* ent  = d_in[1];
    const void* vals = d_in[2];
    const void* W1_1 = d_in[3];
    const void* b1_1 = d_in[4];
    const void* W2_1 = d_in[5];
    const void* b2_1 = d_in[6];
    const void* W1_2 = d_in[7];
    const void* b1_2 = d_in[8];
    const void* W2_2 = d_in[9];
    const void* b2_2 = d_in[10];
    const int* rows  = (const int*)d_in[11];
    const int* cols  = (const int*)d_in[12];

    // ws layout (all 256B-aligned):
    // [flags 4i][partials 64i][row_start (N+1)i][cursor Ni][scol Ei][sval Ef]
    char* w = (char*)d_ws;
    int* flags    = (int*)w;                      w += 256;
    int* partials = (int*)w;                      w += 256;
    int* row_start= (int*)w;                      w += ((N_NODES + 1) * 4 + 255) / 256 * 256;
    int* cursor   = (int*)w;                      w += ((size_t)N_NODES * 4 + 255) / 256 * 256;
    int* scol     = (int*)w;                      w += (size_t)N_EDGES * 4;
    float* sval   = (float*)w;

    k_detect<<<1, 64, 0, stream>>>(user, ent, vals, W1_1, flags);
    k_zero<<<(N_NODES + 256) / 256, 256, 0, stream>>>(row_start);
    k_hist<<<(N_EDGES + 255) / 256, 256, 0, stream>>>(rows, row_start);
    k_scan1<<<SCAN_NB, 256, 0, stream>>>(row_start, partials);
    k_scan2<<<1, 64, 0, stream>>>(partials);
    k_scan3<<<(N_NODES + 256) / 256, 256, 0, stream>>>(row_start, cursor, partials);
    k_scatter<<<(N_EDGES + 255) / 256, 256, 0, stream>>>(rows, cols, vals, cursor, scol, sval, flags);
    k_init<<<(N_NODES * DIM + 255) / 256, 256, 0, stream>>>(user, ent, d_out, flags);
    k_layer1<<<N_NODES / 4, 256, 0, stream>>>(W1_1, b1_1, W2_1, b2_1, d_out, row_start, scol, sval, flags);
    k_layer2<<<N_NODES / 4, 256, 0, stream>>>(W1_2, b1_2, W2_2, b2_2, d_out, row_start, scol, sval, flags);
}

// Round 4
// 647.984 us; speedup vs baseline: 1.6893x; 1.3669x over previous
//
#include <hip/hip_runtime.h>
#include <hip/hip_bf16.h>

#define N_USERS 30000
#define N_NODES 100000
#define DIM 64
#define N_EDGES 1600000
#define SCAN_ELEMS 2048
#define SCAN_NB ((N_NODES + SCAN_ELEMS - 1) / SCAN_ELEMS)  // 49

typedef __hip_bfloat16 bf16;

__device__ __forceinline__ float b2f(bf16 v) { return __bfloat162float(v); }
__device__ __forceinline__ bf16 f2b(float v) { return __float2bfloat16(v); }

// dtype-flexible load/store: f32 flag selects float* vs bf16* interpretation
__device__ __forceinline__ float ld(const void* p, int i, int f32) {
    return f32 ? ((const float*)p)[i] : b2f(((const bf16*)p)[i]);
}
__device__ __forceinline__ void st(void* p, int i, float v, int f32) {
    if (f32) ((float*)p)[i] = v; else ((bf16*)p)[i] = f2b(v);
}

// ---------------------------------------------------------------------------
// Detect fp32 vs bf16 per tensor (bf16 bits read as fp32 -> huge exponents).
// flags: 0=embeddings/out world, 1=entity, 2=vals, 3=weights
// ---------------------------------------------------------------------------
__global__ void k_detect(const void* user, const void* ent, const void* vals,
                         const void* W, int* flags) {
    if (threadIdx.x == 0 && blockIdx.x == 0) {
        const void* ps[4] = { user, ent, vals, W };
        for (int t = 0; t < 4; ++t) {
            const float* f = (const float*)ps[t];
            int ok = 0;
            for (int i = 0; i < 32; ++i) {
                float v = f[i];
                if (v == v && fabsf(v) <= 1e4f) ok++;
            }
            flags[t] = (ok >= 16) ? 1 : 0;
        }
    }
}

// ---------------------------------------------------------------------------
// CSR build: zero counters -> histogram -> 3-phase exclusive scan -> scatter
// ---------------------------------------------------------------------------
__global__ void k_zero(int* __restrict__ cnt) {
    int i = blockIdx.x * blockDim.x + threadIdx.x;
    if (i <= N_NODES) cnt[i] = 0;
}

__global__ void k_hist(const int* __restrict__ rows, int* __restrict__ cnt) {
    int e = blockIdx.x * blockDim.x + threadIdx.x;
    if (e < N_EDGES) atomicAdd(&cnt[rows[e]], 1);
}

__global__ __launch_bounds__(256) void k_scan1(int* __restrict__ cnt,
                                               int* __restrict__ partials) {
    __shared__ int lds[256];
    int t = threadIdx.x;
    int base = blockIdx.x * SCAN_ELEMS + t * 8;
    int local[8];
    int sum = 0;
#pragma unroll
    for (int i = 0; i < 8; ++i) {
        int idx = base + i;
        int v = (idx < N_NODES) ? cnt[idx] : 0;
        local[i] = sum;
        sum += v;
    }
    lds[t] = sum;
    __syncthreads();
    for (int off = 1; off < 256; off <<= 1) {
        int v = (t >= off) ? lds[t - off] : 0;
        __syncthreads();
        lds[t] += v;
        __syncthreads();
    }
    int texcl = (t == 0) ? 0 : lds[t - 1];
#pragma unroll
    for (int i = 0; i < 8; ++i) {
        int idx = base + i;
        if (idx < N_NODES) cnt[idx] = texcl + local[i];
    }
    if (t == 255) partials[blockIdx.x] = lds[255];
}

__global__ void k_scan2(int* __restrict__ partials) {
    if (threadIdx.x == 0 && blockIdx.x == 0) {
        int run = 0;
        for (int i = 0; i < SCAN_NB; ++i) { int v = partials[i]; partials[i] = run; run += v; }
        partials[SCAN_NB] = run;
    }
}

__global__ void k_scan3(int* __restrict__ cnt, int* __restrict__ cursor,
                        const int* __restrict__ partials) {
    int i = blockIdx.x * blockDim.x + threadIdx.x;
    if (i < N_NODES) {
        int v = cnt[i] + partials[i / SCAN_ELEMS];
        cnt[i] = v;
        cursor[i] = v;
    } else if (i == N_NODES) {
        cnt[N_NODES] = partials[SCAN_NB];
    }
}

__global__ void k_scatter(const int* __restrict__ rows, const int* __restrict__ cols,
                          const void* __restrict__ vals, int* __restrict__ cursor,
                          int2* __restrict__ epack, const int* __restrict__ flags) {
    int e = blockIdx.x * blockDim.x + threadIdx.x;
    if (e >= N_EDGES) return;
    int fv = flags[2];
    int pos = atomicAdd(&cursor[rows[e]], 1);
    epack[pos] = make_int2(cols[e], __float_as_int(ld(vals, e, fv)));
}

// ---------------------------------------------------------------------------
// out[:, :64] = concat(user, entity). In fp32 world also stash bf16 copy of
// ego0 into the (not-yet-written) out[:,128:160] byte region (line-aligned,
// 128 B per row) as the layer-1 gather table. k_layer2 overwrites it later.
// ---------------------------------------------------------------------------
__global__ void k_init(const void* __restrict__ user, const void* __restrict__ ent,
                       void* __restrict__ out, const int* __restrict__ flags) {
    int i = blockIdx.x * blockDim.x + threadIdx.x;
    if (i >= N_NODES * DIM) return;
    int fo = flags[0], fe = flags[1];
    int n = i >> 6, d = i & 63;
    float v = (n < N_USERS) ? ld(user, i, fo) : ld(ent, i - N_USERS * DIM, fe);
    st(out, n * 160 + d, v, fo);
    if (fo) ((bf16*)((char*)out + (long)n * 640 + 512))[d] = f2b(v);
}

// ---------------------------------------------------------------------------
// Fused layer 1 (64->64): one wave per 4 rows, no LDS, no barriers.
// Gather: bf16 table, lane sub holds dims {2sub,2sub+1}; halves take edges
// j/j+1; 4 rows round-robin -> 8 gathers in flight.
// Matvec: shuffle-broadcast hp/hm, weights streamed from global (L1/L2-hot).
// ---------------------------------------------------------------------------
__global__ __launch_bounds__(256) void k_layer1(
    const void* __restrict__ W1, const void* __restrict__ b1,
    const void* __restrict__ W2, const void* __restrict__ b2,
    void* __restrict__ out, const int* __restrict__ row_start,
    const int2* __restrict__ epack, bf16* __restrict__ xb,
    const int* __restrict__ flags) {
    int t = threadIdx.x;
    int lane = t & 63, half = lane >> 5, sub = lane & 31;
    int wid = blockIdx.x * 4 + (t >> 6);
    int rbase = wid * 4;
    int fo = flags[0], fw = flags[3];
    const char* gbase = fo ? ((const char*)out + 512) : (const char*)out;
    long gstride = fo ? 640 : 320;

    int r0 = row_start[rbase],     r1 = row_start[rbase + 1];
    int r2 = row_start[rbase + 2], r3 = row_start[rbase + 3];
    int r4 = row_start[rbase + 4];
    int j0 = r0, j1 = r1, j2 = r2, j3 = r3;
    float2 a0 = {0.f, 0.f}, a1 = {0.f, 0.f}, a2 = {0.f, 0.f}, a3 = {0.f, 0.f};

    while (j0 < r1 || j1 < r2 || j2 < r3 || j3 < r4) {
        if (j0 + half < r1) {
            int2 p = epack[j0 + half];
            float val = __int_as_float(p.y);
            unsigned xbits = *(const unsigned*)(gbase + (long)p.x * gstride + sub * 4);
            a0.x += val * __uint_as_float(xbits << 16);
            a0.y += val * __uint_as_float(xbits & 0xffff0000u);
        }
        if (j1 + half < r2) {
            int2 p = epack[j1 + half];
            float val = __int_as_float(p.y);
            unsigned xbits = *(const unsigned*)(gbase + (long)p.x * gstride + sub * 4);
            a1.x += val * __uint_as_float(xbits << 16);
            a1.y += val * __uint_as_float(xbits & 0xffff0000u);
        }
        if (j2 + half < r3) {
            int2 p = epack[j2 + half];
            float val = __int_as_float(p.y);
            unsigned xbits = *(const unsigned*)(gbase + (long)p.x * gstride + sub * 4);
            a2.x += val * __uint_as_float(xbits << 16);
            a2.y += val * __uint_as_float(xbits & 0xffff0000u);
        }
        if (j3 + half < r4) {
            int2 p = epack[j3 + half];
            float val = __int_as_float(p.y);
            unsigned xbits = *(const unsigned*)(gbase + (long)p.x * gstride + sub * 4);
            a3.x += val * __uint_as_float(xbits << 16);
            a3.y += val * __uint_as_float(xbits & 0xffff0000u);
        }
        j0 += 2; j1 += 2; j2 += 2; j3 += 2;
    }

    // halves -> full sum; remap (dim pairs at lane sub) -> per-lane dim
    float hp[4], hm[4];
    float2* accs[4] = { &a0, &a1, &a2, &a3 };
#pragma unroll
    for (int r = 0; r < 4; ++r) {
        float ax = accs[r]->x, ay = accs[r]->y;
        ax += __shfl_xor(ax, 32);
        ay += __shfl_xor(ay, 32);
        float se = __shfl(ax, lane >> 1);
        float so = __shfl(ay, lane >> 1);
        float sde = (lane & 1) ? so : se;
        float h = ld(out, (rbase + r) * 160 + lane, fo);
        hp[r] = h + sde;
        hm[r] = h * sde;
    }

    float bb1 = ld(b1, lane, fw), bb2 = ld(b2, lane, fw);
    float c1[4] = { bb1, bb1, bb1, bb1 };
    float c2[4] = { bb2, bb2, bb2, bb2 };
#pragma unroll 4
    for (int k = 0; k < 64; ++k) {
        float w1 = ld(W1, k * 64 + lane, fw);
        float w2 = ld(W2, k * 64 + lane, fw);
#pragma unroll
        for (int r = 0; r < 4; ++r) {
            c1[r] += __shfl(hp[r], k) * w1;
            c2[r] += __shfl(hm[r], k) * w2;
        }
    }

#pragma unroll
    for (int r = 0; r < 4; ++r) {
        float A1 = c1[r] > 0.f ? c1[r] : 0.01f * c1[r];
        float A2 = c2[r] > 0.f ? c2[r] : 0.01f * c2[r];
        float v = A1 + A2;
        float ss = v * v;
#pragma unroll
        for (int m = 1; m < 64; m <<= 1) ss += __shfl_xor(ss, m, 64);
        float o = v * (1.0f / fmaxf(sqrtf(ss), 1e-12f));
        int n = rbase + r;
        st(out, n * 160 + 64 + lane, o, fo);
        xb[n * 64 + lane] = f2b(o);       // layer-2 gather table
    }
}

// ---------------------------------------------------------------------------
// Fused layer 2 (64->32): same gather structure from xb; dual-half matvec
// (lanes 0..31 sum path, 32..63 bi path), combine via shfl_xor(.,32).
// ---------------------------------------------------------------------------
__global__ __launch_bounds__(256) void k_layer2(
    const void* __restrict__ W1, const void* __restrict__ b1,
    const void* __restrict__ W2, const void* __restrict__ b2,
    void* __restrict__ out, const int* __restrict__ row_start,
    const int2* __restrict__ epack, const bf16* __restrict__ xb,
    const int* __restrict__ flags) {
    int t = threadIdx.x;
    int lane = t & 63, half = lane >> 5, sub = lane & 31;
    int wid = blockIdx.x * 4 + (t >> 6);
    int rbase = wid * 4;
    int fo = flags[0], fw = flags[3];
    const char* gbase = (const char*)xb;

    int r0 = row_start[rbase],     r1 = row_start[rbase + 1];
    int r2 = row_start[rbase + 2], r3 = row_start[rbase + 3];
    int r4 = row_start[rbase + 4];
    int j0 = r0, j1 = r1, j2 = r2, j3 = r3;
    float2 a0 = {0.f, 0.f}, a1 = {0.f, 0.f}, a2 = {0.f, 0.f}, a3 = {0.f, 0.f};

    while (j0 < r1 || j1 < r2 || j2 < r3 || j3 < r4) {
        if (j0 + half < r1) {
            int2 p = epack[j0 + half];
            float val = __int_as_float(p.y);
            unsigned xbits = *(const unsigned*)(gbase + (long)p.x * 128 + sub * 4);
            a0.x += val * __uint_as_float(xbits << 16);
            a0.y += val * __uint_as_float(xbits & 0xffff0000u);
        }
        if (j1 + half < r2) {
            int2 p = epack[j1 + half];
            float val = __int_as_float(p.y);
            unsigned xbits = *(const unsigned*)(gbase + (long)p.x * 128 + sub * 4);
            a1.x += val * __uint_as_float(xbits << 16);
            a1.y += val * __uint_as_float(xbits & 0xffff0000u);
        }
        if (j2 + half < r3) {
            int2 p = epack[j2 + half];
            float val = __int_as_float(p.y);
            unsigned xbits = *(const unsigned*)(gbase + (long)p.x * 128 + sub * 4);
            a2.x += val * __uint_as_float(xbits << 16);
            a2.y += val * __uint_as_float(xbits & 0xffff0000u);
        }
        if (j3 + half < r4) {
            int2 p = epack[j3 + half];
            float val = __int_as_float(p.y);
            unsigned xbits = *(const unsigned*)(gbase + (long)p.x * 128 + sub * 4);
            a3.x += val * __uint_as_float(xbits << 16);
            a3.y += val * __uint_as_float(xbits & 0xffff0000u);
        }
        j0 += 2; j1 += 2; j2 += 2; j3 += 2;
    }

    float hp[4], hm[4];
    float2* accs[4] = { &a0, &a1, &a2, &a3 };
#pragma unroll
    for (int r = 0; r < 4; ++r) {
        float ax = accs[r]->x, ay = accs[r]->y;
        ax += __shfl_xor(ax, 32);
        ay += __shfl_xor(ay, 32);
        float se = __shfl(ax, lane >> 1);
        float so = __shfl(ay, lane >> 1);
        float sde = (lane & 1) ? so : se;
        float h = ld(out, (rbase + r) * 160 + 64 + lane, fo);
        hp[r] = h + sde;
        hm[r] = h * sde;
    }

    // half 0: sum path (W1,b1); half 1: bi path (W2,b2); d = sub
    const char* Wb = half ? (const char*)W2 : (const char*)W1;
    const char* bb = half ? (const char*)b2 : (const char*)b1;
    float bias = fw ? ((const float*)bb)[sub] : b2f(((const bf16*)bb)[sub]);
    float c[4] = { bias, bias, bias, bias };
#pragma unroll 4
    for (int k = 0; k < 64; ++k) {
        int idx = k * 32 + sub;
        float w = fw ? ((const float*)Wb)[idx] : b2f(((const bf16*)Wb)[idx]);
#pragma unroll
        for (int r = 0; r < 4; ++r) {
            float hpk = __shfl(hp[r], k);
            float hmk = __shfl(hm[r], k);
            c[r] += (half ? hmk : hpk) * w;
        }
    }

#pragma unroll
    for (int r = 0; r < 4; ++r) {
        float A = c[r] > 0.f ? c[r] : 0.01f * c[r];
        float v = A + __shfl_xor(A, 32);     // sum_e + bi_e, mirrored halves
        float ss = v * v;
#pragma unroll
        for (int m = 1; m < 32; m <<= 1) ss += __shfl_xor(ss, m, 64);
        float o = v * (1.0f / fmaxf(sqrtf(ss), 1e-12f));
        if (!half) st(out, (rbase + r) * 160 + 128 + sub, o, fo);
    }
}

extern "C" void kernel_launch(void* const* d_in, const int* in_sizes, int n_in,
                              void* d_out, int out_size, void* d_ws, size_t ws_size,
                              hipStream_t stream) {
    const void* user = d_in[0];
    const void* ent  = d_in[1];
    const void* vals = d_in[2];
    const void* W1_1 = d_in[3];
    const void* b1_1 = d_in[4];
    const void* W2_1 = d_in[5];
    const void* b2_1 = d_in[6];
    const void* W1_2 = d_in[7];
    const void* b1_2 = d_in[8];
    const void* W2_2 = d_in[9];
    const void* b2_2 = d_in[10];
    const int* rows  = (const int*)d_in[11];
    const int* cols  = (const int*)d_in[12];

    // ws: [flags][partials][row_start N+1][cursor N][epack E int2][xb N*64 bf16]
    char* w = (char*)d_ws;
    int* flags    = (int*)w;                      w += 256;
    int* partials = (int*)w;                      w += 256;
    int* row_start= (int*)w;                      w += ((N_NODES + 1) * 4 + 255) / 256 * 256;
    int* cursor   = (int*)w;                      w += ((size_t)N_NODES * 4 + 255) / 256 * 256;
    int2* epack   = (int2*)w;                     w += (size_t)N_EDGES * 8;
    bf16* xb      = (bf16*)w;

    k_detect<<<1, 64, 0, stream>>>(user, ent, vals, W1_1, flags);
    k_zero<<<(N_NODES + 256) / 256, 256, 0, stream>>>(row_start);
    k_hist<<<(N_EDGES + 255) / 256, 256, 0, stream>>>(rows, row_start);
    k_scan1<<<SCAN_NB, 256, 0, stream>>>(row_start, partials);
    k_scan2<<<1, 64, 0, stream>>>(partials);
    k_scan3<<<(N_NODES + 256) / 256, 256, 0, stream>>>(row_start, cursor, partials);
    k_scatter<<<(N_EDGES + 255) / 256, 256, 0, stream>>>(rows, cols, vals, cursor, epack, flags);
    k_init<<<(N_NODES * DIM + 255) / 256, 256, 0, stream>>>(user, ent, d_out, flags);
    k_layer1<<<N_NODES / 16, 256, 0, stream>>>(W1_1, b1_1, W2_1, b2_1, d_out, row_start, epack, xb, flags);
    k_layer2<<<N_NODES / 16, 256, 0, stream>>>(W1_2, b1_2, W2_2, b2_2, d_out, row_start, epack, xb, flags);
}

// Round 5
// 533.627 us; speedup vs baseline: 2.0513x; 1.2143x over previous
//
#include <hip/hip_runtime.h>
#include <hip/hip_bf16.h>
#include <string.h>

#define N_USERS 30000
#define N_NODES 100000
#define DIM 64
#define N_EDGES 1600000
#define E_PAD (N_EDGES + N_NODES)   // 1,700,000 — upper bound after per-row even-padding
#define SCAN_ELEMS 2048
#define SCAN_NB ((N_NODES + SCAN_ELEMS - 1) / SCAN_ELEMS)  // 49

typedef __hip_bfloat16 bf16;
typedef __attribute__((ext_vector_type(8))) short short8;   // 8 bf16 = 4 VGPRs
typedef __attribute__((ext_vector_type(4))) float floatx4;  // MFMA accumulator

__device__ __forceinline__ float b2f(bf16 v) { return __bfloat162float(v); }
__device__ __forceinline__ bf16 f2b(float v) { return __float2bfloat16(v); }
__device__ __forceinline__ unsigned short fbits(float v) {
    bf16 b = f2b(v); unsigned short u; memcpy(&u, &b, 2); return u;
}
__device__ __forceinline__ float ubf(unsigned short u) {
    return __uint_as_float((unsigned)u << 16);
}

// dtype-flexible load/store: f32 flag selects float* vs bf16* interpretation
__device__ __forceinline__ float ld(const void* p, int i, int f32) {
    return f32 ? ((const float*)p)[i] : b2f(((const bf16*)p)[i]);
}
__device__ __forceinline__ void st(void* p, int i, float v, int f32) {
    if (f32) ((float*)p)[i] = v; else ((bf16*)p)[i] = f2b(v);
}

// ---------------------------------------------------------------------------
// Detect fp32 vs bf16 per tensor (bf16 bits read as fp32 -> huge exponents).
// flags: 0=embeddings/out world, 1=entity, 2=vals, 3=weights
// ---------------------------------------------------------------------------
__global__ void k_detect(const void* user, const void* ent, const void* vals,
                         const void* W, int* flags) {
    if (threadIdx.x == 0 && blockIdx.x == 0) {
        const void* ps[4] = { user, ent, vals, W };
        for (int t = 0; t < 4; ++t) {
            const float* f = (const float*)ps[t];
            int ok = 0;
            for (int i = 0; i < 32; ++i) {
                float v = f[i];
                if (v == v && fabsf(v) <= 1e4f) ok++;
            }
            flags[t] = (ok >= 16) ? 1 : 0;
        }
    }
}

// ---------------------------------------------------------------------------
// Zero: edge arrays (pad slots must be val=0, col=0) + histogram counters
// ---------------------------------------------------------------------------
__global__ void k_zero(int* __restrict__ cnt, int4* __restrict__ scol4,
                       int4* __restrict__ sval4) {
    int i = blockIdx.x * blockDim.x + threadIdx.x;
    if (i < E_PAD / 4) scol4[i] = make_int4(0, 0, 0, 0);
    if (i < E_PAD / 8) sval4[i] = make_int4(0, 0, 0, 0);
    if (i <= N_NODES) cnt[i] = 0;
}

__global__ void k_hist(const int* __restrict__ rows, int* __restrict__ cnt) {
    int e = blockIdx.x * blockDim.x + threadIdx.x;
    if (e < N_EDGES) atomicAdd(&cnt[rows[e]], 1);
}

// exclusive scan of EVEN-PADDED counts (in-place), block totals to partials
__global__ __launch_bounds__(256) void k_scan1(int* __restrict__ cnt,
                                               int* __restrict__ partials) {
    __shared__ int lds[256];
    int t = threadIdx.x;
    int base = blockIdx.x * SCAN_ELEMS + t * 8;
    int local[8];
    int sum = 0;
#pragma unroll
    for (int i = 0; i < 8; ++i) {
        int idx = base + i;
        int v = (idx < N_NODES) ? ((cnt[idx] + 1) & ~1) : 0;  // pad to even
        local[i] = sum;
        sum += v;
    }
    lds[t] = sum;
    __syncthreads();
    for (int off = 1; off < 256; off <<= 1) {
        int v = (t >= off) ? lds[t - off] : 0;
        __syncthreads();
        lds[t] += v;
        __syncthreads();
    }
    int texcl = (t == 0) ? 0 : lds[t - 1];
#pragma unroll
    for (int i = 0; i < 8; ++i) {
        int idx = base + i;
        if (idx < N_NODES) cnt[idx] = texcl + local[i];
    }
    if (t == 255) partials[blockIdx.x] = lds[255];
}

__global__ void k_scan2(int* __restrict__ partials) {
    int l = threadIdx.x;
    int v = (l < SCAN_NB) ? partials[l] : 0;
    int inc = v;
    for (int off = 1; off < 64; off <<= 1) {
        int u = __shfl_up(inc, off, 64);
        if (l >= off) inc += u;
    }
    if (l < SCAN_NB) partials[l] = inc - v;   // exclusive
    if (l == 63) partials[SCAN_NB] = inc;     // total (padded)
}

__global__ void k_scan3(int* __restrict__ cnt, int* __restrict__ cursor,
                        const int* __restrict__ partials) {
    int i = blockIdx.x * blockDim.x + threadIdx.x;
    if (i < N_NODES) {
        int v = cnt[i] + partials[i / SCAN_ELEMS];
        cnt[i] = v;
        cursor[i] = v;
    } else if (i == N_NODES) {
        cnt[N_NODES] = partials[SCAN_NB];
    }
}

__global__ void k_scatter(const int* __restrict__ rows, const int* __restrict__ cols,
                          const void* __restrict__ vals, int* __restrict__ cursor,
                          int* __restrict__ scol, unsigned short* __restrict__ sval,
                          const int* __restrict__ flags) {
    int e = blockIdx.x * blockDim.x + threadIdx.x;
    if (e >= N_EDGES) return;
    int fv = flags[2];
    int pos = atomicAdd(&cursor[rows[e]], 1);
    scol[pos] = cols[e];
    sval[pos] = fbits(ld(vals, e, fv));
}

// ---------------------------------------------------------------------------
// out[:, :64] = concat(user, entity); xb0 = bf16 gather table of ego0
// ---------------------------------------------------------------------------
__global__ void k_init(const void* __restrict__ user, const void* __restrict__ ent,
                       void* __restrict__ out, bf16* __restrict__ xb0,
                       const int* __restrict__ flags) {
    int i = blockIdx.x * blockDim.x + threadIdx.x;
    if (i >= N_NODES * DIM) return;
    int fo = flags[0], fe = flags[1];
    int n = i >> 6, d = i & 63;
    float v = (n < N_USERS) ? ld(user, i, fo) : ld(ent, i - N_USERS * DIM, fe);
    st(out, n * 160 + d, v, fo);
    xb0[i] = f2b(v);
}

// ---------------------------------------------------------------------------
// Fused layer 1 (64->64): 16 rows/block, 4 waves. Gather: wave owns 4 rows,
// lane = dim, edge (col,val) on the scalar path (uniform indices), ushort
// gathers (128 B/line per edge), 8 in flight. Combine: hp/hm -> LDS bf16,
// MFMA 16x16x32 (wave w = output cols 16w..16w+15), bias-seeded C.
// ---------------------------------------------------------------------------
__global__ __launch_bounds__(256) void k_layer1(
    const void* __restrict__ W1, const void* __restrict__ b1,
    const void* __restrict__ W2, const void* __restrict__ b2,
    void* __restrict__ out, const int* __restrict__ row_start,
    const int* __restrict__ scol, const unsigned short* __restrict__ sval,
    const bf16* __restrict__ xt, bf16* __restrict__ xn,
    const int* __restrict__ flags) {
    __shared__ __align__(16) unsigned short hp_lds[16][72];
    __shared__ __align__(16) unsigned short hm_lds[16][72];
    __shared__ __align__(16) float ssq_lds[16][4];
    int t = threadIdx.x, lane = t & 63, w = t >> 6;
    int sub = lane & 15, quad = lane >> 4;
    int fo = flags[0], fw = flags[3];
    int rbase = blockIdx.x * 16 + w * 4;
    const unsigned short* xu = (const unsigned short*)xt;

    int e0 = row_start[rbase], e1 = row_start[rbase + 1], e2 = row_start[rbase + 2];
    int e3 = row_start[rbase + 3], e4 = row_start[rbase + 4];
    int j0 = e0, j1 = e1, j2 = e2, j3 = e3;
    float a0 = 0.f, a1 = 0.f, a2 = 0.f, a3 = 0.f;
    while (j0 < e1 || j1 < e2 || j2 < e3 || j3 < e4) {
        if (j0 < e1) {
            int c0 = scol[j0], c1c = scol[j0 + 1];
            unsigned vp = *(const unsigned*)&sval[j0];
            a0 += __uint_as_float(vp << 16) * ubf(xu[c0 * 64 + lane]);
            a0 += __uint_as_float(vp & 0xffff0000u) * ubf(xu[c1c * 64 + lane]);
            j0 += 2;
        }
        if (j1 < e2) {
            int c0 = scol[j1], c1c = scol[j1 + 1];
            unsigned vp = *(const unsigned*)&sval[j1];
            a1 += __uint_as_float(vp << 16) * ubf(xu[c0 * 64 + lane]);
            a1 += __uint_as_float(vp & 0xffff0000u) * ubf(xu[c1c * 64 + lane]);
            j1 += 2;
        }
        if (j2 < e3) {
            int c0 = scol[j2], c1c = scol[j2 + 1];
            unsigned vp = *(const unsigned*)&sval[j2];
            a2 += __uint_as_float(vp << 16) * ubf(xu[c0 * 64 + lane]);
            a2 += __uint_as_float(vp & 0xffff0000u) * ubf(xu[c1c * 64 + lane]);
            j2 += 2;
        }
        if (j3 < e4) {
            int c0 = scol[j3], c1c = scol[j3 + 1];
            unsigned vp = *(const unsigned*)&sval[j3];
            a3 += __uint_as_float(vp << 16) * ubf(xu[c0 * 64 + lane]);
            a3 += __uint_as_float(vp & 0xffff0000u) * ubf(xu[c1c * 64 + lane]);
            j3 += 2;
        }
    }
    {
        float s[4] = { a0, a1, a2, a3 };
#pragma unroll
        for (int r = 0; r < 4; ++r) {
            float h = ld(out, (rbase + r) * 160 + lane, fo);
            hp_lds[w * 4 + r][lane] = fbits(h + s[r]);
            hm_lds[w * 4 + r][lane] = fbits(h * s[r]);
        }
    }
    __syncthreads();

    // A fragments: A[m=sub][k=quad*8+j] (+32 for second k-half)
    short8 Ap0 = *(const short8*)((const char*)hp_lds + sub * 144 + quad * 16);
    short8 Ap1 = *(const short8*)((const char*)hp_lds + sub * 144 + 64 + quad * 16);
    short8 Am0 = *(const short8*)((const char*)hm_lds + sub * 144 + quad * 16);
    short8 Am1 = *(const short8*)((const char*)hm_lds + sub * 144 + 64 + quad * 16);

    // B fragments: B[k=quad*8+j][n=wbase+sub], W row-major [64][64]
    int wbase = w * 16;
    short8 B10, B11, B20, B21;
    float bias1, bias2;
    if (fw) {
        const float* w1 = (const float*)W1;
        const float* w2 = (const float*)W2;
#pragma unroll
        for (int j = 0; j < 8; ++j) {
            int k0 = quad * 8 + j;
            B10[j] = (short)fbits(w1[k0 * 64 + wbase + sub]);
            B11[j] = (short)fbits(w1[(k0 + 32) * 64 + wbase + sub]);
            B20[j] = (short)fbits(w2[k0 * 64 + wbase + sub]);
            B21[j] = (short)fbits(w2[(k0 + 32) * 64 + wbase + sub]);
        }
        bias1 = ((const float*)b1)[wbase + sub];
        bias2 = ((const float*)b2)[wbase + sub];
    } else {
        const unsigned short* w1 = (const unsigned short*)W1;
        const unsigned short* w2 = (const unsigned short*)W2;
#pragma unroll
        for (int j = 0; j < 8; ++j) {
            int k0 = quad * 8 + j;
            B10[j] = (short)w1[k0 * 64 + wbase + sub];
            B11[j] = (short)w1[(k0 + 32) * 64 + wbase + sub];
            B20[j] = (short)w2[k0 * 64 + wbase + sub];
            B21[j] = (short)w2[(k0 + 32) * 64 + wbase + sub];
        }
        bias1 = b2f(((const bf16*)b1)[wbase + sub]);
        bias2 = b2f(((const bf16*)b2)[wbase + sub]);
    }

    floatx4 c1; c1[0] = bias1; c1[1] = bias1; c1[2] = bias1; c1[3] = bias1;
    floatx4 c2; c2[0] = bias2; c2[1] = bias2; c2[2] = bias2; c2[3] = bias2;
    c1 = __builtin_amdgcn_mfma_f32_16x16x32_bf16(Ap0, B10, c1, 0, 0, 0);
    c1 = __builtin_amdgcn_mfma_f32_16x16x32_bf16(Ap1, B11, c1, 0, 0, 0);
    c2 = __builtin_amdgcn_mfma_f32_16x16x32_bf16(Am0, B20, c2, 0, 0, 0);
    c2 = __builtin_amdgcn_mfma_f32_16x16x32_bf16(Am1, B21, c2, 0, 0, 0);

    // epilogue: lrelu + add, l2norm over 64 cols (4 waves), store
    float v[4], sp[4];
#pragma unroll
    for (int r = 0; r < 4; ++r) {
        float s1 = c1[r], s2 = c2[r];
        s1 = s1 > 0.f ? s1 : 0.01f * s1;
        s2 = s2 > 0.f ? s2 : 0.01f * s2;
        v[r] = s1 + s2;
        float sq = v[r] * v[r];
        sq += __shfl_xor(sq, 1, 64);
        sq += __shfl_xor(sq, 2, 64);
        sq += __shfl_xor(sq, 4, 64);
        sq += __shfl_xor(sq, 8, 64);
        sp[r] = sq;                         // partial over this wave's 16 cols
    }
    if (sub == 0) {
#pragma unroll
        for (int r = 0; r < 4; ++r) ssq_lds[quad * 4 + r][w] = sp[r];
    }
    __syncthreads();
#pragma unroll
    for (int r = 0; r < 4; ++r) {
        int row = quad * 4 + r;
        floatx4 ps = *(const floatx4*)&ssq_lds[row][0];
        float ss = ps[0] + ps[1] + ps[2] + ps[3];
        float o = v[r] * (1.0f / fmaxf(sqrtf(ss), 1e-12f));
        int n = blockIdx.x * 16 + row;
        st(out, n * 160 + 64 + wbase + sub, o, fo);
        xn[n * 64 + wbase + sub] = f2b(o);
    }
}

// ---------------------------------------------------------------------------
// Fused layer 2 (64->32): same gather; waves 0,1 = sum path (W1, col tiles
// 0/1), waves 2,3 = bi path (W2); cross-path add via LDS; l2norm over 32.
// ---------------------------------------------------------------------------
__global__ __launch_bounds__(256) void k_layer2(
    const void* __restrict__ W1, const void* __restrict__ b1,
    const void* __restrict__ W2, const void* __restrict__ b2,
    void* __restrict__ out, const int* __restrict__ row_start,
    const int* __restrict__ scol, const unsigned short* __restrict__ sval,
    const bf16* __restrict__ xt, const int* __restrict__ flags) {
    __shared__ __align__(16) unsigned short hp_lds[16][72];
    __shared__ __align__(16) unsigned short hm_lds[16][72];
    __shared__ __align__(16) float bi_lds[16][32];
    __shared__ __align__(16) float ssq_lds[16][2];
    int t = threadIdx.x, lane = t & 63, w = t >> 6;
    int sub = lane & 15, quad = lane >> 4;
    int fo = flags[0], fw = flags[3];
    int rbase = blockIdx.x * 16 + w * 4;
    const unsigned short* xu = (const unsigned short*)xt;

    int e0 = row_start[rbase], e1 = row_start[rbase + 1], e2 = row_start[rbase + 2];
    int e3 = row_start[rbase + 3], e4 = row_start[rbase + 4];
    int j0 = e0, j1 = e1, j2 = e2, j3 = e3;
    float a0 = 0.f, a1 = 0.f, a2 = 0.f, a3 = 0.f;
    while (j0 < e1 || j1 < e2 || j2 < e3 || j3 < e4) {
        if (j0 < e1) {
            int c0 = scol[j0], c1c = scol[j0 + 1];
            unsigned vp = *(const unsigned*)&sval[j0];
            a0 += __uint_as_float(vp << 16) * ubf(xu[c0 * 64 + lane]);
            a0 += __uint_as_float(vp & 0xffff0000u) * ubf(xu[c1c * 64 + lane]);
            j0 += 2;
        }
        if (j1 < e2) {
            int c0 = scol[j1], c1c = scol[j1 + 1];
            unsigned vp = *(const unsigned*)&sval[j1];
            a1 += __uint_as_float(vp << 16) * ubf(xu[c0 * 64 + lane]);
            a1 += __uint_as_float(vp & 0xffff0000u) * ubf(xu[c1c * 64 + lane]);
            j1 += 2;
        }
        if (j2 < e3) {
            int c0 = scol[j2], c1c = scol[j2 + 1];
            unsigned vp = *(const unsigned*)&sval[j2];
            a2 += __uint_as_float(vp << 16) * ubf(xu[c0 * 64 + lane]);
            a2 += __uint_as_float(vp & 0xffff0000u) * ubf(xu[c1c * 64 + lane]);
            j2 += 2;
        }
        if (j3 < e4) {
            int c0 = scol[j3], c1c = scol[j3 + 1];
            unsigned vp = *(const unsigned*)&sval[j3];
            a3 += __uint_as_float(vp << 16) * ubf(xu[c0 * 64 + lane]);
            a3 += __uint_as_float(vp & 0xffff0000u) * ubf(xu[c1c * 64 + lane]);
            j3 += 2;
        }
    }
    {
        float s[4] = { a0, a1, a2, a3 };
#pragma unroll
        for (int r = 0; r < 4; ++r) {
            float h = ld(out, (rbase + r) * 160 + 64 + lane, fo);
            hp_lds[w * 4 + r][lane] = fbits(h + s[r]);
            hm_lds[w * 4 + r][lane] = fbits(h * s[r]);
        }
    }
    __syncthreads();

    int path = w >> 1;               // 0: sum(W1), 1: bi(W2)
    int nbase = (w & 1) * 16;        // col tile within 32
    const unsigned short(*hl)[72] = path ? hm_lds : hp_lds;
    short8 A0 = *(const short8*)((const char*)hl + sub * 144 + quad * 16);
    short8 A1 = *(const short8*)((const char*)hl + sub * 144 + 64 + quad * 16);

    const void* W = path ? W2 : W1;
    const void* bb = path ? b2 : b1;
    short8 B0, B1;
    float bias;
    if (fw) {
        const float* wp = (const float*)W;
#pragma unroll
        for (int j = 0; j < 8; ++j) {
            int k0 = quad * 8 + j;
            B0[j] = (short)fbits(wp[k0 * 32 + nbase + sub]);
            B1[j] = (short)fbits(wp[(k0 + 32) * 32 + nbase + sub]);
        }
        bias = ((const float*)bb)[nbase + sub];
    } else {
        const unsigned short* wp = (const unsigned short*)W;
#pragma unroll
        for (int j = 0; j < 8; ++j) {
            int k0 = quad * 8 + j;
            B0[j] = (short)wp[k0 * 32 + nbase + sub];
            B1[j] = (short)wp[(k0 + 32) * 32 + nbase + sub];
        }
        bias = b2f(((const bf16*)bb)[nbase + sub]);
    }

    floatx4 c; c[0] = bias; c[1] = bias; c[2] = bias; c[3] = bias;
    c = __builtin_amdgcn_mfma_f32_16x16x32_bf16(A0, B0, c, 0, 0, 0);
    c = __builtin_amdgcn_mfma_f32_16x16x32_bf16(A1, B1, c, 0, 0, 0);

    float T[4];
#pragma unroll
    for (int r = 0; r < 4; ++r) {
        float x = c[r];
        T[r] = x > 0.f ? x : 0.01f * x;
        if (path == 1) bi_lds[quad * 4 + r][nbase + sub] = T[r];
    }
    __syncthreads();

    float v[4], sp[4];
#pragma unroll
    for (int r = 0; r < 4; ++r) {
        v[r] = T[r] + bi_lds[quad * 4 + r][nbase + sub];  // garbage for path1, unused
        float sq = v[r] * v[r];
        sq += __shfl_xor(sq, 1, 64);
        sq += __shfl_xor(sq, 2, 64);
        sq += __shfl_xor(sq, 4, 64);
        sq += __shfl_xor(sq, 8, 64);
        sp[r] = sq;
    }
    if (path == 0 && sub == 0) {
#pragma unroll
        for (int r = 0; r < 4; ++r) ssq_lds[quad * 4 + r][w & 1] = sp[r];
    }
    __syncthreads();
    if (path == 0) {
#pragma unroll
        for (int r = 0; r < 4; ++r) {
            int row = quad * 4 + r;
            float ss = ssq_lds[row][0] + ssq_lds[row][1];
            float o = v[r] * (1.0f / fmaxf(sqrtf(ss), 1e-12f));
            int n = blockIdx.x * 16 + row;
            st(out, n * 160 + 128 + nbase + sub, o, fo);
        }
    }
}

extern "C" void kernel_launch(void* const* d_in, const int* in_sizes, int n_in,
                              void* d_out, int out_size, void* d_ws, size_t ws_size,
                              hipStream_t stream) {
    const void* user = d_in[0];
    const void* ent  = d_in[1];
    const void* vals = d_in[2];
    const void* W1_1 = d_in[3];
    const void* b1_1 = d_in[4];
    const void* W2_1 = d_in[5];
    const void* b2_1 = d_in[6];
    const void* W1_2 = d_in[7];
    const void* b1_2 = d_in[8];
    const void* W2_2 = d_in[9];
    const void* b2_2 = d_in[10];
    const int* rows  = (const int*)d_in[11];
    const int* cols  = (const int*)d_in[12];

    // ws: [flags][partials][row_start N+1][scol E_PAD i32][sval E_PAD u16]
    //     [xb0 N*64 bf16 (aliased by cursor during CSR build)][xb1 N*64 bf16]
    char* w = (char*)d_ws;
    int* flags            = (int*)w;  w += 256;
    int* partials         = (int*)w;  w += 256;
    int* row_start        = (int*)w;  w += 400128;                 // (N+1)*4 padded
    int* scol             = (int*)w;  w += (size_t)E_PAD * 4;
    unsigned short* sval  = (unsigned short*)w; w += (size_t)E_PAD * 2;
    bf16* xb0             = (bf16*)w; w += (size_t)N_NODES * DIM * 2;
    bf16* xb1             = (bf16*)w;
    int* cursor           = (int*)xb0;   // dead before k_init writes xb0

    k_detect<<<1, 64, 0, stream>>>(user, ent, vals, W1_1, flags);
    k_zero<<<(E_PAD / 4 + 255) / 256, 256, 0, stream>>>(row_start, (int4*)scol, (int4*)sval);
    k_hist<<<(N_EDGES + 255) / 256, 256, 0, stream>>>(rows, row_start);
    k_scan1<<<SCAN_NB, 256, 0, stream>>>(row_start, partials);
    k_scan2<<<1, 64, 0, stream>>>(partials);
    k_scan3<<<(N_NODES + 256) / 256, 256, 0, stream>>>(row_start, cursor, partials);
    k_scatter<<<(N_EDGES + 255) / 256, 256, 0, stream>>>(rows, cols, vals, cursor, scol, sval, flags);
    k_init<<<(N_NODES * DIM + 255) / 256, 256, 0, stream>>>(user, ent, d_out, xb0, flags);
    k_layer1<<<N_NODES / 16, 256, 0, stream>>>(W1_1, b1_1, W2_1, b2_1, d_out, row_start, scol, sval, xb0, xb1, flags);
    k_layer2<<<N_NODES / 16, 256, 0, stream>>>(W1_2, b1_2, W2_2, b2_2, d_out, row_start, scol, sval, xb1, flags);
}

// Round 7
// 471.420 us; speedup vs baseline: 2.3219x; 1.1320x over previous
//
#include <hip/hip_runtime.h>
#include <hip/hip_bf16.h>
#include <string.h>

#define N_USERS 30000
#define N_NODES 100000
#define DIM 64
#define N_EDGES 1600000
#define E_PAD (N_EDGES + 3 * N_NODES)   // rows padded to multiple of 4 edges
#define SCAN_ELEMS 2048
#define SCAN_NB ((N_NODES + SCAN_ELEMS - 1) / SCAN_ELEMS)  // 49

typedef __hip_bfloat16 bf16;
typedef __attribute__((ext_vector_type(8))) short short8;   // 8 bf16 = 4 VGPRs
typedef __attribute__((ext_vector_type(4))) float floatx4;  // MFMA accumulator

__device__ __forceinline__ float b2f(bf16 v) { return __bfloat162float(v); }
__device__ __forceinline__ bf16 f2b(float v) { return __float2bfloat16(v); }
__device__ __forceinline__ unsigned short fbits(float v) {
    bf16 b = f2b(v); unsigned short u; memcpy(&u, &b, 2); return u;
}
__device__ __forceinline__ float ubf(unsigned u) {
    return __uint_as_float(u << 16);
}

// dtype-flexible load/store: f32 flag selects float* vs bf16* interpretation
__device__ __forceinline__ float ld(const void* p, int i, int f32) {
    return f32 ? ((const float*)p)[i] : b2f(((const bf16*)p)[i]);
}
__device__ __forceinline__ void st(void* p, int i, float v, int f32) {
    if (f32) ((float*)p)[i] = v; else ((bf16*)p)[i] = f2b(v);
}

// ---------------------------------------------------------------------------
// Detect fp32 vs bf16 per tensor (bf16 bits read as fp32 -> huge exponents).
// flags: 0=embeddings/out world, 1=entity, 2=vals, 3=weights
// ---------------------------------------------------------------------------
__global__ void k_detect(const void* user, const void* ent, const void* vals,
                         const void* W, int* flags) {
    if (threadIdx.x == 0 && blockIdx.x == 0) {
        const void* ps[4] = { user, ent, vals, W };
        for (int t = 0; t < 4; ++t) {
            const float* f = (const float*)ps[t];
            int ok = 0;
            for (int i = 0; i < 32; ++i) {
                float v = f[i];
                if (v == v && fabsf(v) <= 1e4f) ok++;
            }
            flags[t] = (ok >= 16) ? 1 : 0;
        }
    }
}

__global__ void k_zero(int* __restrict__ cnt) {
    int i = blockIdx.x * blockDim.x + threadIdx.x;
    if (i <= N_NODES) cnt[i] = 0;
}

__global__ void k_hist(const int* __restrict__ rows, int* __restrict__ cnt) {
    int e = (blockIdx.x * blockDim.x + threadIdx.x) * 4;
    if (e >= N_EDGES) return;
    int4 r = *(const int4*)&rows[e];
    atomicAdd(&cnt[r.x], 1);
    atomicAdd(&cnt[r.y], 1);
    atomicAdd(&cnt[r.z], 1);
    atomicAdd(&cnt[r.w], 1);
}

// exclusive scan of counts padded to multiple of 4 (in-place)
__global__ __launch_bounds__(256) void k_scan1(int* __restrict__ cnt,
                                               int* __restrict__ partials) {
    __shared__ int lds[256];
    int t = threadIdx.x;
    int base = blockIdx.x * SCAN_ELEMS + t * 8;
    int local[8];
    int sum = 0;
#pragma unroll
    for (int i = 0; i < 8; ++i) {
        int idx = base + i;
        int v = (idx < N_NODES) ? ((cnt[idx] + 3) & ~3) : 0;  // pad to mult of 4
        local[i] = sum;
        sum += v;
    }
    lds[t] = sum;
    __syncthreads();
    for (int off = 1; off < 256; off <<= 1) {
        int v = (t >= off) ? lds[t - off] : 0;
        __syncthreads();
        lds[t] += v;
        __syncthreads();
    }
    int texcl = (t == 0) ? 0 : lds[t - 1];
#pragma unroll
    for (int i = 0; i < 8; ++i) {
        int idx = base + i;
        if (idx < N_NODES) cnt[idx] = texcl + local[i];
    }
    if (t == 255) partials[blockIdx.x] = lds[255];
}

__global__ void k_scan2(int* __restrict__ partials) {
    int l = threadIdx.x;
    int v = (l < SCAN_NB) ? partials[l] : 0;
    int inc = v;
    for (int off = 1; off < 64; off <<= 1) {
        int u = __shfl_up(inc, off, 64);
        if (l >= off) inc += u;
    }
    if (l < SCAN_NB) partials[l] = inc - v;   // exclusive
    if (l == 63) partials[SCAN_NB] = inc;     // total (padded)
}

__global__ void k_scan3(int* __restrict__ cnt, int* __restrict__ cursor,
                        const int* __restrict__ partials) {
    int i = blockIdx.x * blockDim.x + threadIdx.x;
    if (i < N_NODES) {
        int v = cnt[i] + partials[i / SCAN_ELEMS];
        cnt[i] = v;
        cursor[i] = v;
    } else if (i == N_NODES) {
        cnt[N_NODES] = partials[SCAN_NB];
    }
}

__global__ void k_scatter(const int* __restrict__ rows, const int* __restrict__ cols,
                          const void* __restrict__ vals, int* __restrict__ cursor,
                          int2* __restrict__ epack, const int* __restrict__ flags) {
    int e = blockIdx.x * blockDim.x + threadIdx.x;
    if (e >= N_EDGES) return;
    int fv = flags[2];
    int pos = atomicAdd(&cursor[rows[e]], 1);
    epack[pos] = make_int2(cols[e], __float_as_int(ld(vals, e, fv)));
}

// fill each row's <=3 pad slots with (col=0, val=0)
__global__ void k_pad(const int* __restrict__ row_start,
                      const int* __restrict__ cursor, int2* __restrict__ epack) {
    int i = blockIdx.x * blockDim.x + threadIdx.x;
    if (i >= N_NODES) return;
    int pos = cursor[i], end = row_start[i + 1];
    for (; pos < end; ++pos) epack[pos] = make_int2(0, 0);
}

// ---------------------------------------------------------------------------
// out[:, :64] = concat(user, entity); xb0 = bf16 gather table of ego0
// ---------------------------------------------------------------------------
__global__ void k_init(const void* __restrict__ user, const void* __restrict__ ent,
                       void* __restrict__ out, bf16* __restrict__ xb0,
                       const int* __restrict__ flags) {
    int i = blockIdx.x * blockDim.x + threadIdx.x;
    if (i >= N_NODES * DIM) return;
    int fo = flags[0], fe = flags[1];
    int n = i >> 6, d = i & 63;
    float v = (n < N_USERS) ? ld(user, i, fo) : ld(ent, i - N_USERS * DIM, fe);
    st(out, n * 160 + d, v, fo);
    xb0[i] = f2b(v);
}

// ---------------------------------------------------------------------------
// Gather phase (shared by both layers): wave owns 4 rows, lane = dim.
// Branchless body: 16 gathers/iter (4 rows x 4 edges), masked cols/vals;
// next edge-packs preloaded between gather issue and FMA consumption.
// Macro locals are namespaced eA/eB/ej/ev to avoid collisions.
// ---------------------------------------------------------------------------
#define GATHER_ROW_DECL(r) \
    int ej##r = rs[r], eend##r = rs[r + 1]; \
    bool ev##r = ej##r < eend##r; \
    int4 eA##r = {0,0,0,0}, eB##r = {0,0,0,0}; \
    if (ev##r) { eA##r = ep4[ej##r >> 1]; eB##r = ep4[(ej##r >> 1) + 1]; } \
    float ea##r = 0.f;

#define GATHER_EXTRACT(r) \
    int ec##r##0 = ev##r ? eA##r.x : 0, ec##r##1 = ev##r ? eA##r.z : 0; \
    int ec##r##2 = ev##r ? eB##r.x : 0, ec##r##3 = ev##r ? eB##r.z : 0; \
    float ew##r##0 = ev##r ? __int_as_float(eA##r.y) : 0.f; \
    float ew##r##1 = ev##r ? __int_as_float(eA##r.w) : 0.f; \
    float ew##r##2 = ev##r ? __int_as_float(eB##r.y) : 0.f; \
    float ew##r##3 = ev##r ? __int_as_float(eB##r.w) : 0.f;

#define GATHER_ISSUE(r) \
    unsigned eg##r##0 = xu[ec##r##0 * 64 + lane]; \
    unsigned eg##r##1 = xu[ec##r##1 * 64 + lane]; \
    unsigned eg##r##2 = xu[ec##r##2 * 64 + lane]; \
    unsigned eg##r##3 = xu[ec##r##3 * 64 + lane];

#define GATHER_ADVANCE(r) \
    ej##r += ev##r ? 4 : 0; \
    ev##r = ej##r < eend##r; \
    if (ev##r) { eA##r = ep4[ej##r >> 1]; eB##r = ep4[(ej##r >> 1) + 1]; }

#define GATHER_FMA(r) \
    ea##r += ew##r##0 * ubf(eg##r##0); \
    ea##r += ew##r##1 * ubf(eg##r##1); \
    ea##r += ew##r##2 * ubf(eg##r##2); \
    ea##r += ew##r##3 * ubf(eg##r##3);

#define GATHER_BODY \
    GATHER_ROW_DECL(0) GATHER_ROW_DECL(1) GATHER_ROW_DECL(2) GATHER_ROW_DECL(3) \
    while (ev0 | ev1 | ev2 | ev3) { \
        GATHER_EXTRACT(0) GATHER_EXTRACT(1) GATHER_EXTRACT(2) GATHER_EXTRACT(3) \
        GATHER_ISSUE(0) GATHER_ISSUE(1) GATHER_ISSUE(2) GATHER_ISSUE(3) \
        GATHER_ADVANCE(0) GATHER_ADVANCE(1) GATHER_ADVANCE(2) GATHER_ADVANCE(3) \
        GATHER_FMA(0) GATHER_FMA(1) GATHER_FMA(2) GATHER_FMA(3) \
    }

// ---------------------------------------------------------------------------
// Fused layer 1 (64->64): 16 rows/block, 4 waves. MFMA combine, C/D layout
// col=lane&15, row=(lane>>4)*4+reg. Wave w -> output cols 16w..16w+15.
// ---------------------------------------------------------------------------
__global__ __launch_bounds__(256) void k_layer1(
    const void* __restrict__ W1, const void* __restrict__ b1,
    const void* __restrict__ W2, const void* __restrict__ b2,
    void* __restrict__ out, const int* __restrict__ row_start,
    const int2* __restrict__ epack, const bf16* __restrict__ xt,
    bf16* __restrict__ xn, const int* __restrict__ flags) {
    __shared__ __align__(16) unsigned short hp_lds[16][72];
    __shared__ __align__(16) unsigned short hm_lds[16][72];
    __shared__ __align__(16) float ssq_lds[16][4];
    int t = threadIdx.x, lane = t & 63, w = t >> 6;
    int sub = lane & 15, quad = lane >> 4;
    int fo = flags[0], fw = flags[3];
    int rbase = blockIdx.x * 16 + w * 4;
    const unsigned short* xu = (const unsigned short*)xt;
    const int4* ep4 = (const int4*)epack;

    int rs[5];
#pragma unroll
    for (int r = 0; r < 5; ++r) rs[r] = row_start[rbase + r];
    GATHER_BODY
    {
        float s[4] = { ea0, ea1, ea2, ea3 };
#pragma unroll
        for (int r = 0; r < 4; ++r) {
            float h = ld(out, (rbase + r) * 160 + lane, fo);
            hp_lds[w * 4 + r][lane] = fbits(h + s[r]);
            hm_lds[w * 4 + r][lane] = fbits(h * s[r]);
        }
    }
    __syncthreads();

    // A fragments: A[m=sub][k=quad*8+j] (+32 for second k-half)
    short8 Ap0 = *(const short8*)((const char*)hp_lds + sub * 144 + quad * 16);
    short8 Ap1 = *(const short8*)((const char*)hp_lds + sub * 144 + 64 + quad * 16);
    short8 Am0 = *(const short8*)((const char*)hm_lds + sub * 144 + quad * 16);
    short8 Am1 = *(const short8*)((const char*)hm_lds + sub * 144 + 64 + quad * 16);

    // B fragments: B[k=quad*8+j][n=wbase+sub], W row-major [64][64]
    int wbase = w * 16;
    short8 Bw10, Bw11, Bw20, Bw21;
    float bias1, bias2;
    if (fw) {
        const float* w1 = (const float*)W1;
        const float* w2 = (const float*)W2;
#pragma unroll
        for (int j = 0; j < 8; ++j) {
            int k0 = quad * 8 + j;
            Bw10[j] = (short)fbits(w1[k0 * 64 + wbase + sub]);
            Bw11[j] = (short)fbits(w1[(k0 + 32) * 64 + wbase + sub]);
            Bw20[j] = (short)fbits(w2[k0 * 64 + wbase + sub]);
            Bw21[j] = (short)fbits(w2[(k0 + 32) * 64 + wbase + sub]);
        }
        bias1 = ((const float*)b1)[wbase + sub];
        bias2 = ((const float*)b2)[wbase + sub];
    } else {
        const unsigned short* w1 = (const unsigned short*)W1;
        const unsigned short* w2 = (const unsigned short*)W2;
#pragma unroll
        for (int j = 0; j < 8; ++j) {
            int k0 = quad * 8 + j;
            Bw10[j] = (short)w1[k0 * 64 + wbase + sub];
            Bw11[j] = (short)w1[(k0 + 32) * 64 + wbase + sub];
            Bw20[j] = (short)w2[k0 * 64 + wbase + sub];
            Bw21[j] = (short)w2[(k0 + 32) * 64 + wbase + sub];
        }
        bias1 = b2f(((const bf16*)b1)[wbase + sub]);
        bias2 = b2f(((const bf16*)b2)[wbase + sub]);
    }

    floatx4 c1; c1[0] = bias1; c1[1] = bias1; c1[2] = bias1; c1[3] = bias1;
    floatx4 c2; c2[0] = bias2; c2[1] = bias2; c2[2] = bias2; c2[3] = bias2;
    c1 = __builtin_amdgcn_mfma_f32_16x16x32_bf16(Ap0, Bw10, c1, 0, 0, 0);
    c1 = __builtin_amdgcn_mfma_f32_16x16x32_bf16(Ap1, Bw11, c1, 0, 0, 0);
    c2 = __builtin_amdgcn_mfma_f32_16x16x32_bf16(Am0, Bw20, c2, 0, 0, 0);
    c2 = __builtin_amdgcn_mfma_f32_16x16x32_bf16(Am1, Bw21, c2, 0, 0, 0);

    float v[4], sp[4];
#pragma unroll
    for (int r = 0; r < 4; ++r) {
        float s1 = c1[r], s2 = c2[r];
        s1 = s1 > 0.f ? s1 : 0.01f * s1;
        s2 = s2 > 0.f ? s2 : 0.01f * s2;
        v[r] = s1 + s2;
        float sq = v[r] * v[r];
        sq += __shfl_xor(sq, 1, 64);
        sq += __shfl_xor(sq, 2, 64);
        sq += __shfl_xor(sq, 4, 64);
        sq += __shfl_xor(sq, 8, 64);
        sp[r] = sq;
    }
    if (sub == 0) {
#pragma unroll
        for (int r = 0; r < 4; ++r) ssq_lds[quad * 4 + r][w] = sp[r];
    }
    __syncthreads();
#pragma unroll
    for (int r = 0; r < 4; ++r) {
        int row = quad * 4 + r;
        floatx4 ps = *(const floatx4*)&ssq_lds[row][0];
        float ss = ps[0] + ps[1] + ps[2] + ps[3];
        float o = v[r] * (1.0f / fmaxf(sqrtf(ss), 1e-12f));
        int n = blockIdx.x * 16 + row;
        st(out, n * 160 + 64 + wbase + sub, o, fo);
        xn[n * 64 + wbase + sub] = f2b(o);
    }
}

// ---------------------------------------------------------------------------
// Fused layer 2 (64->32): same gather; waves 0,1 = sum path (W1), waves 2,3 =
// bi path (W2); cross-path add via LDS; l2norm over 32.
// ---------------------------------------------------------------------------
__global__ __launch_bounds__(256) void k_layer2(
    const void* __restrict__ W1, const void* __restrict__ b1,
    const void* __restrict__ W2, const void* __restrict__ b2,
    void* __restrict__ out, const int* __restrict__ row_start,
    const int2* __restrict__ epack, const bf16* __restrict__ xt,
    const int* __restrict__ flags) {
    __shared__ __align__(16) unsigned short hp_lds[16][72];
    __shared__ __align__(16) unsigned short hm_lds[16][72];
    __shared__ __align__(16) float bi_lds[16][32];
    __shared__ __align__(16) float ssq_lds[16][2];
    int t = threadIdx.x, lane = t & 63, w = t >> 6;
    int sub = lane & 15, quad = lane >> 4;
    int fo = flags[0], fw = flags[3];
    int rbase = blockIdx.x * 16 + w * 4;
    const unsigned short* xu = (const unsigned short*)xt;
    const int4* ep4 = (const int4*)epack;

    int rs[5];
#pragma unroll
    for (int r = 0; r < 5; ++r) rs[r] = row_start[rbase + r];
    GATHER_BODY
    {
        float s[4] = { ea0, ea1, ea2, ea3 };
#pragma unroll
        for (int r = 0; r < 4; ++r) {
            float h = ld(out, (rbase + r) * 160 + 64 + lane, fo);
            hp_lds[w * 4 + r][lane] = fbits(h + s[r]);
            hm_lds[w * 4 + r][lane] = fbits(h * s[r]);
        }
    }
    __syncthreads();

    int path = w >> 1;               // 0: sum(W1), 1: bi(W2)
    int nbase = (w & 1) * 16;        // col tile within 32
    const unsigned short(*hl)[72] = path ? hm_lds : hp_lds;
    short8 Af0 = *(const short8*)((const char*)hl + sub * 144 + quad * 16);
    short8 Af1 = *(const short8*)((const char*)hl + sub * 144 + 64 + quad * 16);

    const void* W = path ? W2 : W1;
    const void* bb = path ? b2 : b1;
    short8 Bf0, Bf1;
    float bias;
    if (fw) {
        const float* wp = (const float*)W;
#pragma unroll
        for (int j = 0; j < 8; ++j) {
            int k0 = quad * 8 + j;
            Bf0[j] = (short)fbits(wp[k0 * 32 + nbase + sub]);
            Bf1[j] = (short)fbits(wp[(k0 + 32) * 32 + nbase + sub]);
        }
        bias = ((const float*)bb)[nbase + sub];
    } else {
        const unsigned short* wp = (const unsigned short*)W;
#pragma unroll
        for (int j = 0; j < 8; ++j) {
            int k0 = quad * 8 + j;
            Bf0[j] = (short)wp[k0 * 32 + nbase + sub];
            Bf1[j] = (short)wp[(k0 + 32) * 32 + nbase + sub];
        }
        bias = b2f(((const bf16*)bb)[nbase + sub]);
    }

    floatx4 c; c[0] = bias; c[1] = bias; c[2] = bias; c[3] = bias;
    c = __builtin_amdgcn_mfma_f32_16x16x32_bf16(Af0, Bf0, c, 0, 0, 0);
    c = __builtin_amdgcn_mfma_f32_16x16x32_bf16(Af1, Bf1, c, 0, 0, 0);

    float T[4];
#pragma unroll
    for (int r = 0; r < 4; ++r) {
        float x = c[r];
        T[r] = x > 0.f ? x : 0.01f * x;
        if (path == 1) bi_lds[quad * 4 + r][nbase + sub] = T[r];
    }
    __syncthreads();

    float v[4], sp[4];
#pragma unroll
    for (int r = 0; r < 4; ++r) {
        v[r] = T[r] + bi_lds[quad * 4 + r][nbase + sub];
        float sq = v[r] * v[r];
        sq += __shfl_xor(sq, 1, 64);
        sq += __shfl_xor(sq, 2, 64);
        sq += __shfl_xor(sq, 4, 64);
        sq += __shfl_xor(sq, 8, 64);
        sp[r] = sq;
    }
    if (path == 0 && sub == 0) {
#pragma unroll
        for (int r = 0; r < 4; ++r) ssq_lds[quad * 4 + r][w & 1] = sp[r];
    }
    __syncthreads();
    if (path == 0) {
#pragma unroll
        for (int r = 0; r < 4; ++r) {
            int row = quad * 4 + r;
            float ss = ssq_lds[row][0] + ssq_lds[row][1];
            float o = v[r] * (1.0f / fmaxf(sqrtf(ss), 1e-12f));
            int n = blockIdx.x * 16 + row;
            st(out, n * 160 + 128 + nbase + sub, o, fo);
        }
    }
}

extern "C" void kernel_launch(void* const* d_in, const int* in_sizes, int n_in,
                              void* d_out, int out_size, void* d_ws, size_t ws_size,
                              hipStream_t stream) {
    const void* user = d_in[0];
    const void* ent  = d_in[1];
    const void* vals = d_in[2];
    const void* W1_1 = d_in[3];
    const void* b1_1 = d_in[4];
    const void* W2_1 = d_in[5];
    const void* b2_1 = d_in[6];
    const void* W1_2 = d_in[7];
    const void* b1_2 = d_in[8];
    const void* W2_2 = d_in[9];
    const void* b2_2 = d_in[10];
    const int* rows  = (const int*)d_in[11];
    const int* cols  = (const int*)d_in[12];

    // ws: [flags][partials][row_start N+1][epack E_PAD int2][xb0][xb1]
    char* w = (char*)d_ws;
    int* flags     = (int*)w;  w += 256;
    int* partials  = (int*)w;  w += 256;
    int* row_start = (int*)w;  w += 400128;                 // (N+1)*4 padded
    int2* epack    = (int2*)w; w += (size_t)E_PAD * 8;
    bf16* xb0      = (bf16*)w; w += (size_t)N_NODES * DIM * 2;
    bf16* xb1      = (bf16*)w;
    int* cursor    = (int*)xb0;   // dead before k_init writes xb0

    k_detect<<<1, 64, 0, stream>>>(user, ent, vals, W1_1, flags);
    k_zero<<<(N_NODES + 256) / 256, 256, 0, stream>>>(row_start);
    k_hist<<<(N_EDGES / 4 + 255) / 256, 256, 0, stream>>>(rows, row_start);
    k_scan1<<<SCAN_NB, 256, 0, stream>>>(row_start, partials);
    k_scan2<<<1, 64, 0, stream>>>(partials);
    k_scan3<<<(N_NODES + 256) / 256, 256, 0, stream>>>(row_start, cursor, partials);
    k_scatter<<<(N_EDGES + 255) / 256, 256, 0, stream>>>(rows, cols, vals, cursor, epack, flags);
    k_pad<<<(N_NODES + 255) / 256, 256, 0, stream>>>(row_start, cursor, epack);
    k_init<<<(N_NODES * DIM + 255) / 256, 256, 0, stream>>>(user, ent, d_out, xb0, flags);
    k_layer1<<<N_NODES / 16, 256, 0, stream>>>(W1_1, b1_1, W2_1, b2_1, d_out, row_start, epack, xb0, xb1, flags);
    k_layer2<<<N_NODES / 16, 256, 0, stream>>>(W1_2, b1_2, W2_2, b2_2, d_out, row_start, epack, xb1, flags);
}